// Round 2
// baseline (4890.455 us; speedup 1.0000x reference)
//
#include <hip/hip_runtime.h>

typedef short bf16x8 __attribute__((ext_vector_type(8)));
typedef float f32x4 __attribute__((ext_vector_type(4)));
typedef unsigned short us8 __attribute__((ext_vector_type(8)));

#define B_ 256
#define T_ 1024
#define H_ 512
#define E_ 256
#define O_ 256
#define V_ 256

// Prepped operands in device globals: no ws_size assumptions, graph-safe,
// rewritten deterministically every launch.
__device__ __align__(16) unsigned short g_P[V_ * H_];     // P = emb@Wx^T + b, bf16 (256 KB)
__device__ __align__(16) unsigned short g_Whf[H_ * H_];   // Wh in MFMA B-frag layout (512 KB)
__device__ __align__(16) unsigned short g_Wdf[O_ * H_];   // Wd in MFMA B-frag layout (256 KB)

__device__ __forceinline__ unsigned short f2bf(float f) {
    union { float f; unsigned int u; } v; v.f = f;
    unsigned int r = v.u + 0x7fffu + ((v.u >> 16) & 1u);   // RNE
    return (unsigned short)(r >> 16);
}
__device__ __forceinline__ float bf2f(unsigned short s) {
    union { unsigned int u; float f; } v; v.u = ((unsigned int)s) << 16;
    return v.f;
}

// ---------------- K1a: P[v][n] = b[n] + sum_e emb[v][e] * Wx[n][e] ----------------
__global__ void k_embWx(const float* __restrict__ emb, const float* __restrict__ W,
                        const float* __restrict__ bb) {
    __shared__ float e[E_];
    int v = blockIdx.x;
    e[threadIdx.x] = emb[(size_t)v * E_ + threadIdx.x];
    __syncthreads();
#pragma unroll
    for (int rep = 0; rep < 2; rep++) {
        int n = threadIdx.x + rep * 256;
        const float4* wr4 = (const float4*)(W + (size_t)n * (E_ + H_));  // Wx row = W[n][0:256]
        float s = bb[n];
        for (int k = 0; k < E_ / 4; k++) {
            float4 wv = wr4[k];
            s += e[4*k] * wv.x + e[4*k+1] * wv.y + e[4*k+2] * wv.z + e[4*k+3] * wv.w;
        }
        g_P[v * H_ + n] = f2bf(s);
    }
}

// ---------------- K1b/K1c: weight -> MFMA B-fragment layout (bf16) ----------------
// Tile (nt,kt): lane l, elem j holds  Wmat[n = nt*16 + (l&15)][k = kt*32 + (l>>4)*8 + j]
__global__ void k_fragWh(const float* __restrict__ W) {
    int gid = blockIdx.x * blockDim.x + threadIdx.x;   // 512 tiles * 64 lanes
    int l = gid & 63, tile = gid >> 6;
    int kt = tile & 15, nt = tile >> 4;
    int n = nt * 16 + (l & 15), k0 = kt * 32 + (l >> 4) * 8;
    const float* src = W + (size_t)n * (E_ + H_) + E_ + k0;   // Wh = W[:,256:]
#pragma unroll
    for (int j = 0; j < 8; j++) g_Whf[(size_t)gid * 8 + j] = f2bf(src[j]);
}
__global__ void k_fragWd(const float* __restrict__ Wd) {
    int gid = blockIdx.x * blockDim.x + threadIdx.x;   // 256 tiles * 64 lanes
    int l = gid & 63, tile = gid >> 6;
    int kt = tile & 15, nt = tile >> 4;
    int n = nt * 16 + (l & 15), k0 = kt * 32 + (l >> 4) * 8;
    const float* src = Wd + (size_t)n * H_ + k0;
#pragma unroll
    for (int j = 0; j < 8; j++) g_Wdf[(size_t)gid * 8 + j] = f2bf(src[j]);
}

// ---------------- K2: recurrence ----------------
// 16 blocks x 16 batch rows; 8 waves; wave w owns n-tiles 4w..4w+3 (64 outputs).
// Wh B-frags: kt 0..11 pinned in 192 VGPRs (amdgpu_waves_per_eu(2,2) forces the
// 256-reg budget; plain launch_bounds(512,2) let the backend cap at 128 last round),
// kt 12..15 in 128 KB LDS. h double-buffered in LDS (2x16 KB, XOR-swizzled
// byte ^= (row&7)<<4) -> ONE raw barrier per step, lgkmcnt-only (hs HBM stores are
// never vmcnt-drained inside the loop). Input term u = P[x[r,t]] is loaded straight
// from L2 into the MFMA C-operand (acc init) — no lds_u, no second barrier.
__attribute__((amdgpu_waves_per_eu(2, 2)))
__global__ void __launch_bounds__(512) k_rnn(const int* __restrict__ x,
                                             const float* __restrict__ h0,
                                             float* __restrict__ out) {
    __shared__ __align__(16) unsigned short lds_B[128 * 512];     // 128 KB: kt 12..15
    __shared__ __align__(16) unsigned short lds_h[2][16 * 512];   // 2 x 16 KB
    const int tid = threadIdx.x;
    const int w = tid >> 6, l = tid & 63;
    const int hi = l >> 4, lo = l & 15;
    const int r0 = blockIdx.x * 16;
    const int nb = w * 64 + lo;                 // n for nt=0 (n = nb + nt*16)
    const int sw = (lo & 7) << 4;               // A-read swizzle

    // pinned B-fragments, kt 0..11  (4 nt x 12 kt = 48 frags = 192 VGPRs)
    bf16x8 breg[4][12];
#pragma unroll
    for (int nt = 0; nt < 4; nt++)
#pragma unroll
        for (int kt = 0; kt < 12; kt++)
            breg[nt][kt] = *(const bf16x8*)(g_Whf + ((w * 4 + nt) * 16 + kt) * 512 + l * 8);

    // LDS-resident B-fragments, kt 12..15
#pragma unroll
    for (int nt = 0; nt < 4; nt++)
#pragma unroll
        for (int kk = 0; kk < 4; kk++) {
            bf16x8 v = *(const bf16x8*)(g_Whf + ((w * 4 + nt) * 16 + 12 + kk) * 512 + l * 8);
            *(bf16x8*)((char*)lds_B + (w * 16 + nt * 4 + kk) * 1024 + l * 16) = v;
        }

    // stage h0 (fp32 -> bf16, swizzled) into buffer 0
    {
        int row = tid >> 5;
        int c = (tid & 31) * 16;
        const float* hsrc = h0 + (size_t)(r0 + row) * H_ + c;
        us8 va, vb;
#pragma unroll
        for (int i = 0; i < 8; i++) ((unsigned short*)&va)[i] = f2bf(hsrc[i]);
#pragma unroll
        for (int i = 0; i < 8; i++) ((unsigned short*)&vb)[i] = f2bf(hsrc[8 + i]);
        char* hb = (char*)lds_h[0] + row * 1024;
        int cb = c * 2;
        *(us8*)(hb + ((cb)      ^ ((row & 7) << 4))) = va;
        *(us8*)(hb + ((cb + 16) ^ ((row & 7) << 4))) = vb;
    }

    // x prefetch for t=0 (thread's 4 batch rows: r = hi*4+rg)
    int xs0 = x[(r0 + hi * 4 + 0) * T_];
    int xs1 = x[(r0 + hi * 4 + 1) * T_];
    int xs2 = x[(r0 + hi * 4 + 2) * T_];
    int xs3 = x[(r0 + hi * 4 + 3) * T_];

    // per-thread hs base offsets (32-bit; max ~134M < 2^31)
    unsigned ro0 = (unsigned)(r0 + hi * 4 + 0) * (T_ * H_) + nb;
    unsigned ro1 = (unsigned)(r0 + hi * 4 + 1) * (T_ * H_) + nb;
    unsigned ro2 = (unsigned)(r0 + hi * 4 + 2) * (T_ * H_) + nb;
    unsigned ro3 = (unsigned)(r0 + hi * 4 + 3) * (T_ * H_) + nb;

    __syncthreads();

    unsigned short* hs = (unsigned short*)out;   // hs[b,t] bf16 in-place in d_out

#pragma unroll 1
    for (int t = 0; t < T_; t++) {
        const int c = t & 1;
        // acc init = u = P[x[r,t]][n]  (C-operand carries the input term)
        f32x4 acc[4];
        {
            int xb0 = (xs0 << 9) + nb, xb1 = (xs1 << 9) + nb;
            int xb2 = (xs2 << 9) + nb, xb3 = (xs3 << 9) + nb;
#pragma unroll
            for (int nt = 0; nt < 4; nt++) {
                acc[nt][0] = bf2f(g_P[xb0 + nt * 16]);
                acc[nt][1] = bf2f(g_P[xb1 + nt * 16]);
                acc[nt][2] = bf2f(g_P[xb2 + nt * 16]);
                acc[nt][3] = bf2f(g_P[xb3 + nt * 16]);
            }
        }
        // prefetch x for t+1 (hidden under MFMA phase)
        {
            int tn = (t < T_ - 1) ? t + 1 : t;
            xs0 = x[(r0 + hi * 4 + 0) * T_ + tn];
            xs1 = x[(r0 + hi * 4 + 1) * T_ + tn];
            xs2 = x[(r0 + hi * 4 + 2) * T_ + tn];
            xs3 = x[(r0 + hi * 4 + 3) * T_ + tn];
        }

        const char* hb = (const char*)lds_h[c];
#pragma unroll
        for (int kt = 0; kt < 12; kt++) {
            bf16x8 a = *(const bf16x8*)(hb + lo * 1024 + ((kt * 64 + hi * 16) ^ sw));
            acc[0] = __builtin_amdgcn_mfma_f32_16x16x32_bf16(a, breg[0][kt], acc[0], 0, 0, 0);
            acc[1] = __builtin_amdgcn_mfma_f32_16x16x32_bf16(a, breg[1][kt], acc[1], 0, 0, 0);
            acc[2] = __builtin_amdgcn_mfma_f32_16x16x32_bf16(a, breg[2][kt], acc[2], 0, 0, 0);
            acc[3] = __builtin_amdgcn_mfma_f32_16x16x32_bf16(a, breg[3][kt], acc[3], 0, 0, 0);
        }
        const char* bb = (const char*)lds_B + w * 16384 + l * 16;
#pragma unroll
        for (int kk = 0; kk < 4; kk++) {
            bf16x8 a = *(const bf16x8*)(hb + lo * 1024 + (((12 + kk) * 64 + hi * 16) ^ sw));
            bf16x8 b0 = *(const bf16x8*)(bb + (0 * 4 + kk) * 1024);
            bf16x8 b1 = *(const bf16x8*)(bb + (1 * 4 + kk) * 1024);
            bf16x8 b2 = *(const bf16x8*)(bb + (2 * 4 + kk) * 1024);
            bf16x8 b3 = *(const bf16x8*)(bb + (3 * 4 + kk) * 1024);
            acc[0] = __builtin_amdgcn_mfma_f32_16x16x32_bf16(a, b0, acc[0], 0, 0, 0);
            acc[1] = __builtin_amdgcn_mfma_f32_16x16x32_bf16(a, b1, acc[1], 0, 0, 0);
            acc[2] = __builtin_amdgcn_mfma_f32_16x16x32_bf16(a, b2, acc[2], 0, 0, 0);
            acc[3] = __builtin_amdgcn_mfma_f32_16x16x32_bf16(a, b3, acc[3], 0, 0, 0);
        }

        // epilogue: h_next = tanh(acc); write hs (global, NOT drained) + lds_h[c^1]
        char* hw = (char*)lds_h[c ^ 1];
        const unsigned tb = (unsigned)t << 9;   // t*H_
#pragma unroll
        for (int nt = 0; nt < 4; nt++) {
#pragma unroll
            for (int rg = 0; rg < 4; rg++) {
                const int r = hi * 4 + rg;       // C/D row = (lane>>4)*4 + reg  [m89]
                float v = acc[nt][rg];
                float ex = __expf(v + v);
                float th = 1.f - __fdividef(2.f, ex + 1.f);   // tanh
                unsigned short hv = f2bf(th);
                unsigned ro = (rg == 0) ? ro0 : (rg == 1) ? ro1 : (rg == 2) ? ro2 : ro3;
                hs[ro + tb + nt * 16] = hv;
                *(unsigned short*)(hw + r * 1024 + ((2 * (nb + nt * 16)) ^ ((r & 7) << 4))) = hv;
            }
        }

        // single barrier: LDS visibility only (no vmcnt drain of hs stores)
        __builtin_amdgcn_sched_barrier(0);
        asm volatile("s_waitcnt lgkmcnt(0)" ::: "memory");
        __builtin_amdgcn_s_barrier();
        __builtin_amdgcn_sched_barrier(0);
    }

    // h_final (fp32) from lds_h[0]  (step 1023 wrote buffer 0; loop-end barrier covers)
    float* hfin = out + (size_t)B_ * T_ * O_;
#pragma unroll
    for (int nt = 0; nt < 4; nt++)
#pragma unroll
        for (int rg = 0; rg < 4; rg++) {
            const int r = hi * 4 + rg;
            const int n = nb + nt * 16;
            unsigned short hv = *(const unsigned short*)((const char*)lds_h[0] + r * 1024 +
                                                         ((2 * n) ^ ((r & 7) << 4)));
            hfin[(r0 + r) * H_ + n] = bf2f(hv);
        }
}

// ---------------- K3: outputs = hs @ Wd^T + bd, in-place over hs slots ----------------
// 1024 blocks x 256 (b,t)-rows; wave w: 32 rows x all 256 outs. Reads bf16 hs from the
// exact d_out bytes it later overwrites with fp32 outputs (reads precede writes per wave).
__launch_bounds__(512, 2)
__global__ void k_out(const float* __restrict__ bd, float* out) {
    int tid = threadIdx.x;
    int w = tid >> 6, l = tid & 63;
    int hi = l >> 4, lo = l & 15;
    size_t m0 = (size_t)blockIdx.x * 256 + w * 32;
    const unsigned short* hsb = (const unsigned short*)out;
    float bdv[16];
#pragma unroll
    for (int nt = 0; nt < 16; nt++) bdv[nt] = bd[nt * 16 + lo];
    f32x4 acc[2][16];
#pragma unroll
    for (int m = 0; m < 2; m++)
#pragma unroll
        for (int nt = 0; nt < 16; nt++) { acc[m][nt][0] = 0.f; acc[m][nt][1] = 0.f; acc[m][nt][2] = 0.f; acc[m][nt][3] = 0.f; }
#pragma unroll 2
    for (int kt = 0; kt < 16; kt++) {
        bf16x8 a0 = *(const bf16x8*)(hsb + (m0 + lo) * 512 + kt * 32 + hi * 8);
        bf16x8 a1 = *(const bf16x8*)(hsb + (m0 + 16 + lo) * 512 + kt * 32 + hi * 8);
#pragma unroll
        for (int nt = 0; nt < 16; nt++) {
            bf16x8 bf = *(const bf16x8*)(g_Wdf + (size_t)(nt * 16 + kt) * 512 + l * 8);
            acc[0][nt] = __builtin_amdgcn_mfma_f32_16x16x32_bf16(a0, bf, acc[0][nt], 0, 0, 0);
            acc[1][nt] = __builtin_amdgcn_mfma_f32_16x16x32_bf16(a1, bf, acc[1][nt], 0, 0, 0);
        }
    }
#pragma unroll
    for (int m = 0; m < 2; m++)
#pragma unroll
        for (int nt = 0; nt < 16; nt++)
#pragma unroll
            for (int rg = 0; rg < 4; rg++) {
                size_t row = m0 + m * 16 + hi * 4 + rg;
                out[row * O_ + nt * 16 + lo] = acc[m][nt][rg] + bdv[nt];
            }
}

extern "C" void kernel_launch(void* const* d_in, const int* in_sizes, int n_in,
                              void* d_out, int out_size, void* d_ws, size_t ws_size,
                              hipStream_t stream) {
    const int*   x   = (const int*)d_in[0];
    const float* h0  = (const float*)d_in[1];
    const float* emb = (const float*)d_in[2];
    const float* W   = (const float*)d_in[3];
    const float* b   = (const float*)d_in[4];
    const float* Wd  = (const float*)d_in[5];
    const float* bd  = (const float*)d_in[6];
    float* out = (float*)d_out;

    k_embWx<<<dim3(V_), dim3(256), 0, stream>>>(emb, W, b);
    k_fragWh<<<dim3(128), dim3(256), 0, stream>>>(W);
    k_fragWd<<<dim3(64), dim3(256), 0, stream>>>(Wd);
    k_rnn<<<dim3(16), dim3(512), 0, stream>>>(x, h0, out);
    k_out<<<dim3(1024), dim3(512), 0, stream>>>(bd, out);
}